// Round 6
// baseline (1014.012 us; speedup 1.0000x reference)
//
#include <hip/hip_runtime.h>
#include <hip/hip_bf16.h>

// Problem constants (B=2, D=64, H=W=96)
constexpr int B_    = 2;
constexpr int D_    = 64;
constexpr int N_    = 9216;      // 96*96
constexpr int ITERS = 4;

constexpr int MTQ     = 128;          // queries per workgroup (2 m-waves x 64)
constexpr int MBF     = N_ / MTQ;     // 72 m-blocks
constexpr int KS      = 4;            // key-split factor
constexpr int KEYS_WG = N_ / KS;      // 2304 keys per workgroup
constexpr int KTILES  = KEYS_WG / 128;// 18 key tiles of 128
constexpr int NWG     = B_ * MBF * KS;// 576 flash workgroups
constexpr int PB      = 144;          // prep n-blocks of 64

constexpr float KBW  = 0.3f;
constexpr float STEP = 0.5f;
constexpr float C2   = 0.43280851226668905f;  // KBW * log2(e)

using short8   = __attribute__((ext_vector_type(8))) short;
using float16v = __attribute__((ext_vector_type(16))) float;

__device__ __forceinline__ unsigned short f2bf(float f) {
  union { float f; unsigned u; } v; v.f = f;
  unsigned u = v.u;
  unsigned r = (u + 0x7fffu + ((u >> 16) & 1u)) >> 16;   // RNE
  return (unsigned short)r;
}

#if __has_builtin(__builtin_amdgcn_cvt_pk_bf16_f32)
typedef __attribute__((ext_vector_type(2))) __bf16 bf16x2;
__device__ __forceinline__ unsigned pk2bf(float a, float b) {
  bf16x2 r = __builtin_amdgcn_cvt_pk_bf16_f32(a, b);   // low <- a, high <- b, RNE
  union { bf16x2 h; unsigned u; } v; v.h = r; return v.u;
}
#else
__device__ __forceinline__ unsigned pk2bf(float a, float b) {
  return (unsigned)f2bf(a) | ((unsigned)f2bf(b) << 16);
}
#endif

// Async global->LDS DMA, 16 B/lane; lds_base wave-uniform, lane i -> base+16i.
__device__ __forceinline__ void dma16(const unsigned short* g,
                                      unsigned short* lds_base, int lane) {
#if __has_builtin(__builtin_amdgcn_global_load_lds)
  __builtin_amdgcn_global_load_lds(
      (const __attribute__((address_space(1))) unsigned int*)g,
      (__attribute__((address_space(3))) unsigned int*)lds_base, 16, 0, 0);
#else
  *(int4*)((char*)lds_base + lane * 16) = *(const int4*)g;
#endif
}

// ---------------------------------------------------------------------------
// prep: x_in (fp32 [b][d][n]) -> out slice 0 (copy), Xbf bf16 [b][d][n],
//       XT bf16 [b][n][d] (LDS transpose)
// ---------------------------------------------------------------------------
__global__ void prep_kernel(const float* __restrict__ xin, float* __restrict__ out,
                            unsigned short* __restrict__ XT,
                            unsigned short* __restrict__ Xbf)
{
  const int bx = blockIdx.x;
  const int nb = bx % PB, b = bx / PB;
  const int n0 = nb * 64;
  const int tid = threadIdx.x;
  __shared__ float tile[64 * 65];

  #pragma unroll
  for (int r = 0; r < 16; ++r) {
    int idx = r * 256 + tid;
    int d = idx >> 6, j = idx & 63;
    float v = xin[((size_t)b * 64 + d) * N_ + n0 + j];
    out[(((size_t)b * 5 + 0) * 64 + d) * N_ + n0 + j] = v;
    Xbf[((size_t)b * 64 + d) * N_ + n0 + j] = f2bf(v);
    tile[d * 65 + j] = v;
  }
  __syncthreads();
  #pragma unroll
  for (int r = 0; r < 16; ++r) {
    int idx = r * 256 + tid;
    int nl = idx >> 6, d = idx & 63;
    XT[((size_t)b * N_ + n0 + nl) * 64 + d] = f2bf(tile[d * 65 + nl]);
  }
}

// ---------------------------------------------------------------------------
// flash: wg = (b, 128-query m-block, key-split). Waves split 2(m) x 2(k):
// wave (wm,wk) owns queries wm*64..+63 (2 m-tiles) and key subtiles
// s = 2wk, 2wk+1 of each staged 128-key tile -> af/b2 fragments are shared
// across the 2 m-tiles (halves LDS frag reads vs pure m-split).
//
// THE σ-TRICK: GEMM1's A-fragment reads key row σ(c) = c with bits 2<->3
// swapped. The MFMA C-layout (row=(p&3)+8(p>>2)+4h) then yields W already
// in A-operand order (a20=q[0..3], a21=q[4..7]) — the R5 bpermute+cndmask
// transform (and its 5.3M conflict cycles) vanishes at zero cost.
// Colsum is permutation-invariant; self-term cancellation preserved.
//
// Queries pre-scaled by C2 -> w = exp2(S) directly (no per-element mul).
//   GEMM1: S[i][m'] = sum_d XT[key σ(i)][d] * (C2*XT[query m'][d])
//   GEMM2: acc[m][d] += sum_n W[m][n] * Xbf[d][n]
// ---------------------------------------------------------------------------
__global__ void __launch_bounds__(256, 3) flash_kernel(
    const unsigned short* __restrict__ XT,
    const unsigned short* __restrict__ Xbf,
    float* __restrict__ pacc, float* __restrict__ pcs)
{
  const int bx   = blockIdx.x;
  const int ks   = bx & 3;
  const int mb   = (bx >> 2) % MBF;
  const int b    = bx / (MBF * KS);
  const int tid  = threadIdx.x;
  const int wave = tid >> 6, lane = tid & 63;
  const int wm = wave >> 1, wk = wave & 1;
  const int c = lane & 31, h = lane >> 5;
  const int cp = (c & 0x13) | ((c & 4) << 1) | ((c & 8) >> 1);  // swap bits 2,3
  const int m0 = mb * MTQ;

  const unsigned short* XTb = XT  + (size_t)b * N_ * 64;
  const unsigned short* Xb  = Xbf + (size_t)b * 64 * N_;

  __shared__ char smem[33280];
  unsigned short* sXT = (unsigned short*)smem;            // [128 key][64 d]
  unsigned short* sXB = (unsigned short*)(smem + 16384);  // [64 d][128 n]
  float* accbuf = (float*)smem;                           // epilogue alias (32KB)
  float* csbuf  = (float*)(smem + 32768);                 // 128 floats

  // resident query fragments (B-operand), pre-scaled by C2:
  // lane&31 = m', k-elem = kstep*16 + h*8 + j
  short8 qf[2][4];
  #pragma unroll
  for (int mt = 0; mt < 2; ++mt)
    #pragma unroll
    for (int k = 0; k < 4; ++k) {
      short8 raw = *(const short8*)(XTb +
          (size_t)(m0 + wm * 64 + mt * 32 + c) * 64 + k * 16 + h * 8);
      unsigned o[4];
      const unsigned* rw = (const unsigned*)&raw;
      #pragma unroll
      for (int p4 = 0; p4 < 4; ++p4) {
        union { unsigned u; float f; } lo, hi;
        lo.u = rw[p4] << 16; hi.u = rw[p4] & 0xffff0000u;
        o[p4] = pk2bf(lo.f * C2, hi.f * C2);
      }
      qf[mt][k] = *(const short8*)o;
    }

  float16v zv;
  #pragma unroll
  for (int p = 0; p < 16; ++p) zv[p] = 0.f;
  float16v acc[2][2];
  acc[0][0] = zv; acc[0][1] = zv; acc[1][0] = zv; acc[1][1] = zv;
  float cs[2] = {0.f, 0.f};

  // DMA lane coords
  const int xt_rr = lane >> 3, xt_sc = lane & 7;   // 8 rows x 8 chunks
  const int xb_rr = lane >> 4, xb_sc = lane & 15;  // 4 rows x 16 chunks

  int n0g = ks * KEYS_WG;
  for (int t = 0; t < KTILES; ++t, n0g += 128) {
    __syncthreads();   // prior tile fully consumed
    // ---- DMA staging; swizzle on global side: LDS[row][sc] = chunk sc^(row&7)
    #pragma unroll
    for (int ii = 0; ii < 4; ++ii) {
      int row = wave * 32 + ii * 8 + xt_rr;                 // key row
      int gc  = xt_sc ^ (row & 7);
      dma16(XTb + (size_t)(n0g + row) * 64 + gc * 8,
            sXT + (wave * 32 + ii * 8) * 64, lane);
    }
    #pragma unroll
    for (int ii = 0; ii < 4; ++ii) {
      int row = wave * 16 + ii * 4 + xb_rr;                 // d row
      int gc  = xb_sc ^ (row & 7);
      dma16(Xb + (size_t)row * N_ + n0g + gc * 8,
            sXB + (wave * 16 + ii * 4) * 128, lane);
    }
    __syncthreads();   // tile ready

    #pragma unroll
    for (int s2 = 0; s2 < 2; ++s2) {
      const int s = wk * 2 + s2;            // this wave's key subtile of 32

      // A-frags (keys, σ-permuted rows): row = s*32 + σ(c)
      short8 af[4];
      #pragma unroll
      for (int k = 0; k < 4; ++k)
        af[k] = *(const short8*)(sXT + (s * 32 + cp) * 64 +
                                 ((k * 2 + h) ^ (cp & 7)) * 8);
      // B-frags (X): row = dt*32+c, chunk = 4s + 2*k2 + h
      short8 b2[2][2];
      #pragma unroll
      for (int k2 = 0; k2 < 2; ++k2)
        #pragma unroll
        for (int dt = 0; dt < 2; ++dt)
          b2[k2][dt] = *(const short8*)(sXB + (dt * 32 + c) * 128 +
                                        ((4 * s + 2 * k2 + h) ^ (c & 7)) * 8);

      #pragma unroll
      for (int mt = 0; mt < 2; ++mt) {
        // ---- GEMM1 (S = C2 * dot, thanks to pre-scaled queries) ----
        float16v S = zv;
        #pragma unroll
        for (int k = 0; k < 4; ++k)
          S = __builtin_amdgcn_mfma_f32_32x32x16_bf16(af[k], qf[mt][k], S, 0, 0, 0);

        // ---- exp2 + packed bf16 + colsum (from the ROUNDED weights) ----
        unsigned q[8];
        #pragma unroll
        for (int g = 0; g < 8; ++g) {
          float w0 = __builtin_amdgcn_exp2f(S[2 * g]);
          float w1 = __builtin_amdgcn_exp2f(S[2 * g + 1]);
          unsigned u = pk2bf(w0, w1);
          q[g] = u;
          union { unsigned u; float f; } lo, hi;
          lo.u = u << 16; hi.u = u & 0xffff0000u;
          cs[mt] += lo.f; cs[mt] += hi.f;
        }

        // σ-permute makes q[] already A-operand ordered: no cross-lane moves
        union { unsigned d[4]; short8 s; } a20, a21;
        a20.d[0] = q[0]; a20.d[1] = q[1]; a20.d[2] = q[2]; a20.d[3] = q[3];
        a21.d[0] = q[4]; a21.d[1] = q[5]; a21.d[2] = q[6]; a21.d[3] = q[7];

        // ---- GEMM2: acc[m][d] += W[m][n] * X[d][n] ----
        #pragma unroll
        for (int dt = 0; dt < 2; ++dt)
          acc[mt][dt] = __builtin_amdgcn_mfma_f32_32x32x16_bf16(
              a20.s, b2[0][dt], acc[mt][dt], 0, 0, 0);
        #pragma unroll
        for (int dt = 0; dt < 2; ++dt)
          acc[mt][dt] = __builtin_amdgcn_mfma_f32_32x32x16_bf16(
              a21.s, b2[1][dt], acc[mt][dt], 0, 0, 0);
      }
    }
  }

  // -------- epilogue: wk-pair reduction via LDS, then direct writes --------
  __syncthreads();
  for (int i = tid; i < 8192; i += 256) accbuf[i] = 0.f;
  if (tid < 128) csbuf[tid] = 0.f;
  __syncthreads();

  #pragma unroll
  for (int mt = 0; mt < 2; ++mt) {
    atomicAdd(&csbuf[wm * 64 + mt * 32 + c], cs[mt]);   // both h-halves add
    #pragma unroll
    for (int dt = 0; dt < 2; ++dt)
      #pragma unroll
      for (int p = 0; p < 16; ++p) {
        int m_l = wm * 64 + mt * 32 + (p & 3) + 8 * (p >> 2) + 4 * h;
        atomicAdd(&accbuf[m_l * 64 + dt * 32 + c], acc[mt][dt][p]);
      }
  }
  __syncthreads();

  for (int i = tid; i < 8192; i += 256)
    pacc[(size_t)bx * 8192 + i] = accbuf[i];
  if (tid < 128) pcs[(size_t)bx * 128 + tid] = csbuf[tid];
}

// ---------------------------------------------------------------------------
// combine: sum KS partials, normalize, blend with x_cur (= out slice t),
// write out slice t+1 + next iteration's Xbf / XT (bf16). grid: B_*MBF.
// ---------------------------------------------------------------------------
__global__ void combine_kernel(const float* __restrict__ pacc,
                               const float* __restrict__ pcs,
                               float* __restrict__ out,
                               unsigned short* __restrict__ XT,
                               unsigned short* __restrict__ Xbf, int t)
{
  const int bx = blockIdx.x;
  const int mb = bx % MBF, b = bx / MBF;
  const int m0 = mb * MTQ;
  const int tid = threadIdx.x;
  __shared__ float accs[128 * 65];
  __shared__ float cst[128];
  const int base = (b * MBF + mb) * KS;

  #pragma unroll
  for (int r = 0; r < 32; ++r) {
    int idx = r * 256 + tid;                  // m = idx>>6, d = idx&63
    float s = 0.f;
    #pragma unroll
    for (int k = 0; k < KS; ++k) s += pacc[(size_t)(base + k) * 8192 + idx];
    accs[(idx >> 6) * 65 + (idx & 63)] = s;
  }
  if (tid < 128) {
    float cv = 0.f;
    #pragma unroll
    for (int k = 0; k < KS; ++k) cv += pcs[(size_t)(base + k) * 128 + tid];
    cst[tid] = cv;
  }
  __syncthreads();

  #pragma unroll
  for (int r = 0; r < 32; ++r) {
    int idx = r * 256 + tid;
    int m = idx & 127, d = idx >> 7;          // m fastest -> coalesced global n
    float a = accs[m * 65 + d];
    size_t obase = (((size_t)b * 5 + t) * 64 + d) * N_ + m0 + m;
    float xc = out[obase];
    float v = STEP * (a / cst[m]) + (1.f - STEP) * xc;
    out[obase + (size_t)64 * N_] = v;         // slice t+1
    Xbf[((size_t)b * 64 + d) * N_ + m0 + m] = f2bf(v);
    accs[m * 65 + d] = v;                     // in-place for transpose pass
  }
  __syncthreads();

  #pragma unroll
  for (int r = 0; r < 32; ++r) {
    int idx = r * 256 + tid;
    int m = idx >> 6, d = idx & 63;           // d fastest -> coalesced XT row
    XT[((size_t)b * N_ + m0 + m) * 64 + d] = f2bf(accs[m * 65 + d]);
  }
}

// ---------------------------------------------------------------------------
extern "C" void kernel_launch(void* const* d_in, const int* in_sizes, int n_in,
                              void* d_out, int out_size, void* d_ws, size_t ws_size,
                              hipStream_t stream)
{
  (void)in_sizes; (void)n_in; (void)out_size; (void)ws_size;
  const float* xin = (const float*)d_in[0];
  float* out = (float*)d_out;
  char* ws = (char*)d_ws;

  // workspace layout (23,887,872 B total — same footprint as R1-R5):
  unsigned short* XT  = (unsigned short*)(ws);             //  2,359,296 B
  unsigned short* Xbf = (unsigned short*)(ws +  2359296);  //  2,359,296 B
  float*          pacc = (float*)(ws +  4718592);          // 18,874,368 B (576*8192*4)
  float*          pcs  = (float*)(ws + 23592960);          //    294,912 B (576*128*4)

  prep_kernel<<<B_ * PB, 256, 0, stream>>>(xin, out, XT, Xbf);
  for (int t = 0; t < ITERS; ++t) {
    flash_kernel<<<NWG, 256, 0, stream>>>(XT, Xbf, pacc, pcs);
    combine_kernel<<<B_ * MBF, 256, 0, stream>>>(pacc, pcs, out, XT, Xbf, t);
  }
}

// Round 7
// 418.443 us; speedup vs baseline: 2.4233x; 2.4233x over previous
//
#include <hip/hip_runtime.h>
#include <hip/hip_bf16.h>

// Problem constants (B=2, D=64, H=W=96)
constexpr int B_    = 2;
constexpr int D_    = 64;
constexpr int N_    = 9216;      // 96*96
constexpr int ITERS = 4;

constexpr int MTQ     = 128;          // queries per workgroup (m-split: 32/wave)
constexpr int MBF     = N_ / MTQ;     // 72 m-blocks
constexpr int KS      = 4;            // key-split factor
constexpr int KEYS_WG = N_ / KS;      // 2304 keys per workgroup
constexpr int KTILES  = KEYS_WG / 128;// 18 key tiles of 128
constexpr int NWG     = B_ * MBF * KS;// 576 flash workgroups
constexpr int PB      = 144;          // prep n-blocks of 64

constexpr float KBW  = 0.3f;
constexpr float STEP = 0.5f;
constexpr float C2   = 0.43280851226668905f;  // KBW * log2(e)

using short8   = __attribute__((ext_vector_type(8))) short;
using float16v = __attribute__((ext_vector_type(16))) float;
typedef __attribute__((ext_vector_type(2))) __bf16 bf16x2;

__device__ __forceinline__ unsigned short f2bf(float f) {
  union { float f; unsigned u; } v; v.f = f;
  unsigned u = v.u;
  unsigned r = (u + 0x7fffu + ((u >> 16) & 1u)) >> 16;   // RNE
  return (unsigned short)r;
}

#if __has_builtin(__builtin_amdgcn_cvt_pk_bf16_f32)
__device__ __forceinline__ unsigned pk2bf(float a, float b) {
  bf16x2 r = __builtin_amdgcn_cvt_pk_bf16_f32(a, b);   // low <- a, high <- b, RNE
  union { bf16x2 h; unsigned u; } v; v.h = r; return v.u;
}
#else
__device__ __forceinline__ unsigned pk2bf(float a, float b) {
  return (unsigned)f2bf(a) | ((unsigned)f2bf(b) << 16);
}
#endif

// cs += lo(u) + hi(u) where u is a packed bf16 pair — 1 instr if dot2 exists.
__device__ __forceinline__ float csum2(unsigned u, float cs) {
#if __has_builtin(__builtin_amdgcn_fdot2_f32_bf16)
  union { unsigned x; bf16x2 h; } a, o;
  a.x = u; o.x = 0x3f803f80u;                          // (1.0, 1.0) bf16
  return __builtin_amdgcn_fdot2_f32_bf16(a.h, o.h, cs, false);
#else
  union { unsigned u; float f; } lo, hi;
  lo.u = u << 16; hi.u = u & 0xffff0000u;
  return cs + lo.f + hi.f;
#endif
}

// Async global->LDS DMA, 16 B/lane; lds_base wave-uniform, lane i -> base+16i.
__device__ __forceinline__ void dma16(const unsigned short* g,
                                      unsigned short* lds_base, int lane) {
#if __has_builtin(__builtin_amdgcn_global_load_lds)
  __builtin_amdgcn_global_load_lds(
      (const __attribute__((address_space(1))) unsigned int*)g,
      (__attribute__((address_space(3))) unsigned int*)lds_base, 16, 0, 0);
#else
  *(int4*)((char*)lds_base + lane * 16) = *(const int4*)g;
#endif
}

// ---------------------------------------------------------------------------
// prep: x_in (fp32 [b][d][n]) -> out slice 0 (copy), Xbf bf16 [b][d][n],
//       XT bf16 [b][n][d] (LDS transpose)
// ---------------------------------------------------------------------------
__global__ void prep_kernel(const float* __restrict__ xin, float* __restrict__ out,
                            unsigned short* __restrict__ XT,
                            unsigned short* __restrict__ Xbf)
{
  const int bx = blockIdx.x;
  const int nb = bx % PB, b = bx / PB;
  const int n0 = nb * 64;
  const int tid = threadIdx.x;
  __shared__ float tile[64 * 65];

  #pragma unroll
  for (int r = 0; r < 16; ++r) {
    int idx = r * 256 + tid;
    int d = idx >> 6, j = idx & 63;
    float v = xin[((size_t)b * 64 + d) * N_ + n0 + j];
    out[(((size_t)b * 5 + 0) * 64 + d) * N_ + n0 + j] = v;
    Xbf[((size_t)b * 64 + d) * N_ + n0 + j] = f2bf(v);
    tile[d * 65 + j] = v;
  }
  __syncthreads();
  #pragma unroll
  for (int r = 0; r < 16; ++r) {
    int idx = r * 256 + tid;
    int nl = idx >> 6, d = idx & 63;
    XT[((size_t)b * N_ + n0 + nl) * 64 + d] = f2bf(tile[d * 65 + nl]);
  }
}

// ---------------------------------------------------------------------------
// flash: R5 structure (m-split waves, 97.5 µs baseline) + the R6-validated
// σ-trick. wg = (b, 128-query m-block, key-split); wave w owns queries
// m0+w*32..+31; all 4 waves share each staged 128-key tile.
//
// σ-TRICK (validated R6): GEMM1's A-fragment reads key row σ(c) = c with
// bits 2<->3 swapped. MFMA C-layout (row=(p&3)+8(p>>2)+4h) then delivers W
// already in A-operand order (a20=q[0..3], a21=q[4..7]) — no bpermutes, no
// selects (R5 spent 5.3M LDS-conflict cycles on them). Colsum is
// permutation-invariant; self-term cancellation preserved.
//
// Queries pre-scaled by C2 -> w = exp2(S) directly.
//   GEMM1: S[i][m'] = sum_d XT[key σ(i)][d] * (C2*XT[query m'][d])
//   GEMM2: acc[m][d] += sum_n W[m][n] * Xbf[d][n]
// Outputs wave-disjoint -> direct global writes, no reduction epilogue.
// ---------------------------------------------------------------------------
__global__ void __launch_bounds__(256, 3) flash_kernel(
    const unsigned short* __restrict__ XT,
    const unsigned short* __restrict__ Xbf,
    float* __restrict__ pacc, float* __restrict__ pcs)
{
  const int bx   = blockIdx.x;
  const int ks   = bx & 3;
  const int mb   = (bx >> 2) % MBF;
  const int b    = bx / (MBF * KS);
  const int tid  = threadIdx.x;
  const int wave = tid >> 6, lane = tid & 63;
  const int c = lane & 31, h = lane >> 5;
  const int cp = (c & 0x13) | ((c & 4) << 1) | ((c & 8) >> 1);  // swap bits 2,3
  const int m0 = mb * MTQ;
  const int bpaddr = (lane ^ 32) << 2;      // ds_bpermute byte index (epilogue)

  const unsigned short* XTb = XT  + (size_t)b * N_ * 64;
  const unsigned short* Xb  = Xbf + (size_t)b * 64 * N_;

  __shared__ unsigned short sXT[128 * 64];  // [key][d], chunk-swizzled
  __shared__ unsigned short sXB[64 * 128];  // [d][n],  chunk-swizzled

  // wave's resident query fragments (B-operand), pre-scaled by C2
  short8 qf[4];
  #pragma unroll
  for (int k = 0; k < 4; ++k) {
    short8 raw = *(const short8*)(XTb +
        (size_t)(m0 + wave * 32 + c) * 64 + k * 16 + h * 8);
    unsigned o[4];
    const unsigned* rw = (const unsigned*)&raw;
    #pragma unroll
    for (int p4 = 0; p4 < 4; ++p4) {
      union { unsigned u; float f; } lo, hi;
      lo.u = rw[p4] << 16; hi.u = rw[p4] & 0xffff0000u;
      o[p4] = pk2bf(lo.f * C2, hi.f * C2);
    }
    qf[k] = *(const short8*)o;
  }

  float16v zv;
  #pragma unroll
  for (int p = 0; p < 16; ++p) zv[p] = 0.f;
  float16v acc[2];
  acc[0] = zv; acc[1] = zv;
  float cs = 0.f;

  // DMA lane coords
  const int xt_rr = lane >> 3, xt_sc = lane & 7;   // 8 rows x 8 chunks
  const int xb_rr = lane >> 4, xb_sc = lane & 15;  // 4 rows x 16 chunks

  int n0g = ks * KEYS_WG;
  for (int t = 0; t < KTILES; ++t, n0g += 128) {
    __syncthreads();   // prior tile fully consumed
    // ---- DMA staging; swizzle on global side: LDS[row][sc] = chunk sc^(row&7)
    #pragma unroll
    for (int ii = 0; ii < 4; ++ii) {
      int row = wave * 32 + ii * 8 + xt_rr;                 // key row
      int gc  = xt_sc ^ (row & 7);
      dma16(XTb + (size_t)(n0g + row) * 64 + gc * 8,
            sXT + (wave * 32 + ii * 8) * 64, lane);
    }
    #pragma unroll
    for (int ii = 0; ii < 4; ++ii) {
      int row = wave * 16 + ii * 4 + xb_rr;                 // d row
      int gc  = xb_sc ^ (row & 7);
      dma16(Xb + (size_t)row * N_ + n0g + gc * 8,
            sXB + (wave * 16 + ii * 4) * 128, lane);
    }
    __syncthreads();   // tile ready

    #pragma unroll
    for (int s = 0; s < 4; ++s) {           // 4 key subtiles of 32
      // A-frags (keys, σ-permuted rows): row = s*32 + σ(c)
      short8 af[4];
      #pragma unroll
      for (int k = 0; k < 4; ++k)
        af[k] = *(const short8*)(sXT + (s * 32 + cp) * 64 +
                                 ((k * 2 + h) ^ (cp & 7)) * 8);

      float16v S = zv;
      #pragma unroll
      for (int k = 0; k < 4; ++k)
        S = __builtin_amdgcn_mfma_f32_32x32x16_bf16(af[k], qf[k], S, 0, 0, 0);

      // exp2 + packed bf16; colsum from the ROUNDED weights (dot2 with ones)
      unsigned q[8];
      #pragma unroll
      for (int g = 0; g < 8; ++g) {
        float w0 = __builtin_amdgcn_exp2f(S[2 * g]);
        float w1 = __builtin_amdgcn_exp2f(S[2 * g + 1]);
        unsigned u = pk2bf(w0, w1);
        q[g] = u;
        cs = csum2(u, cs);
      }

      // σ-permute: q[] is already A-operand ordered — no cross-lane moves
      union { unsigned d[4]; short8 s; } a20, a21;
      a20.d[0] = q[0]; a20.d[1] = q[1]; a20.d[2] = q[2]; a20.d[3] = q[3];
      a21.d[0] = q[4]; a21.d[1] = q[5]; a21.d[2] = q[6]; a21.d[3] = q[7];

      // B-frags (X): row = dt*32+c, chunk = 4s + 2*k2 + h
      short8 b20[2], b21[2];
      #pragma unroll
      for (int dt = 0; dt < 2; ++dt) {
        b20[dt] = *(const short8*)(sXB + (dt * 32 + c) * 128 + ((4 * s + h)     ^ (c & 7)) * 8);
        b21[dt] = *(const short8*)(sXB + (dt * 32 + c) * 128 + ((4 * s + 2 + h) ^ (c & 7)) * 8);
      }
      #pragma unroll
      for (int dt = 0; dt < 2; ++dt)
        acc[dt] = __builtin_amdgcn_mfma_f32_32x32x16_bf16(a20.s, b20[dt], acc[dt], 0, 0, 0);
      #pragma unroll
      for (int dt = 0; dt < 2; ++dt)
        acc[dt] = __builtin_amdgcn_mfma_f32_32x32x16_bf16(a21.s, b21[dt], acc[dt], 0, 0, 0);
    }
  }

  // -------- epilogue: wave-disjoint outputs, direct global writes ----------
  union { float f; int i; } cu; cu.f = cs;
  cu.i = __builtin_amdgcn_ds_bpermute(bpaddr, cu.i);
  float cst = cs + cu.f;                     // both h-halves hold the total
  if (h == 0) pcs[(size_t)bx * 128 + wave * 32 + c] = cst;

  float* pw = pacc + (size_t)bx * (MTQ * 64);
  #pragma unroll
  for (int dt = 0; dt < 2; ++dt)
    #pragma unroll
    for (int p = 0; p < 16; ++p) {
      int m = wave * 32 + (p & 3) + 8 * (p >> 2) + 4 * h;
      pw[m * 64 + dt * 32 + c] = acc[dt][p];
    }
}

// ---------------------------------------------------------------------------
// combine: sum KS partials, normalize, blend with x_cur (= out slice t),
// write out slice t+1 + next iteration's Xbf / XT (bf16). grid: B_*MBF.
// ---------------------------------------------------------------------------
__global__ void combine_kernel(const float* __restrict__ pacc,
                               const float* __restrict__ pcs,
                               float* __restrict__ out,
                               unsigned short* __restrict__ XT,
                               unsigned short* __restrict__ Xbf, int t)
{
  const int bx = blockIdx.x;
  const int mb = bx % MBF, b = bx / MBF;
  const int m0 = mb * MTQ;
  const int tid = threadIdx.x;
  __shared__ float accs[128 * 65];
  __shared__ float cst[128];
  const int base = (b * MBF + mb) * KS;

  #pragma unroll
  for (int r = 0; r < 32; ++r) {
    int idx = r * 256 + tid;                  // m = idx>>6, d = idx&63
    float s = 0.f;
    #pragma unroll
    for (int k = 0; k < KS; ++k) s += pacc[(size_t)(base + k) * 8192 + idx];
    accs[(idx >> 6) * 65 + (idx & 63)] = s;
  }
  if (tid < 128) {
    float cv = 0.f;
    #pragma unroll
    for (int k = 0; k < KS; ++k) cv += pcs[(size_t)(base + k) * 128 + tid];
    cst[tid] = cv;
  }
  __syncthreads();

  #pragma unroll
  for (int r = 0; r < 32; ++r) {
    int idx = r * 256 + tid;
    int m = idx & 127, d = idx >> 7;          // m fastest -> coalesced global n
    float a = accs[m * 65 + d];
    size_t obase = (((size_t)b * 5 + t) * 64 + d) * N_ + m0 + m;
    float xc = out[obase];
    float v = STEP * (a / cst[m]) + (1.f - STEP) * xc;
    out[obase + (size_t)64 * N_] = v;         // slice t+1
    Xbf[((size_t)b * 64 + d) * N_ + m0 + m] = f2bf(v);
    accs[m * 65 + d] = v;                     // in-place for transpose pass
  }
  __syncthreads();

  #pragma unroll
  for (int r = 0; r < 32; ++r) {
    int idx = r * 256 + tid;
    int m = idx >> 6, d = idx & 63;           // d fastest -> coalesced XT row
    XT[((size_t)b * N_ + m0 + m) * 64 + d] = f2bf(accs[m * 65 + d]);
  }
}

// ---------------------------------------------------------------------------
extern "C" void kernel_launch(void* const* d_in, const int* in_sizes, int n_in,
                              void* d_out, int out_size, void* d_ws, size_t ws_size,
                              hipStream_t stream)
{
  (void)in_sizes; (void)n_in; (void)out_size; (void)ws_size;
  const float* xin = (const float*)d_in[0];
  float* out = (float*)d_out;
  char* ws = (char*)d_ws;

  // workspace layout (23,887,872 B total — same footprint as R1-R6):
  unsigned short* XT  = (unsigned short*)(ws);             //  2,359,296 B
  unsigned short* Xbf = (unsigned short*)(ws +  2359296);  //  2,359,296 B
  float*          pacc = (float*)(ws +  4718592);          // 18,874,368 B (576*8192*4)
  float*          pcs  = (float*)(ws + 23592960);          //    294,912 B (576*128*4)

  prep_kernel<<<B_ * PB, 256, 0, stream>>>(xin, out, XT, Xbf);
  for (int t = 0; t < ITERS; ++t) {
    flash_kernel<<<NWG, 256, 0, stream>>>(XT, Xbf, pacc, pcs);
    combine_kernel<<<B_ * MBF, 256, 0, stream>>>(pacc, pcs, out, XT, Xbf, t);
  }
}